// Round 2
// baseline (305.298 us; speedup 1.0000x reference)
//
#include <hip/hip_runtime.h>

// BinCat: out[b,i,:] = cats[idx(b,i),:] where
// idx = sum_j (1 - x[b,i,j]) << (19 - j)  ==  0xFFFFF ^ pack(x).
// B=4096, I=16, L=20, D=64. Pure random gather from a 256 MB table;
// latency-bound unless enough gathers are in flight.

#define BATCH 4096
#define I_DIM 16
#define LENGTH 20
#define DIM 64

#define ROWS (BATCH * I_DIM)          // 65536
#define ROWS_PER_BLOCK 64             // 4 gathers/thread
#define THREADS 256
#define PASSES ((ROWS_PER_BLOCK * (DIM / 4)) / THREADS)   // 4
#define STAGE_ITERS ((ROWS_PER_BLOCK * LENGTH) / THREADS) // 5

// Native 16-byte vector: accepted by __builtin_nontemporal_{load,store},
// lowers to global_{load,store}_dwordx4.
typedef __attribute__((ext_vector_type(4))) float f32x4;

__global__ __launch_bounds__(THREADS) void bincat_gather(
    const int* __restrict__ x,      // (ROWS, LENGTH) int32 in {0,1}
    const float* __restrict__ cats, // (2^20, DIM) fp32
    float* __restrict__ out)        // (ROWS, DIM) fp32
{
    __shared__ int sbits[ROWS_PER_BLOCK * LENGTH]; // 1280 ints = 5 KB
    __shared__ int sidx[ROWS_PER_BLOCK];

    const int t = threadIdx.x;
    const int row0 = blockIdx.x * ROWS_PER_BLOCK;

    // Stage this block's x bits: 1280 contiguous ints, coalesced.
    // Non-temporal: x is single-use; don't let it evict cats from L2/L3.
    const int base = row0 * LENGTH;
    #pragma unroll
    for (int i = 0; i < STAGE_ITERS; ++i) {
        const int k = t + i * THREADS;
        sbits[k] = __builtin_nontemporal_load(&x[base + k]);
    }
    __syncthreads();

    // Lanes 0..63 (one full wave) each fold one row's 20 bits.
    // bits are {0,1}: pack with OR, complement with XOR.
    if (t < ROWS_PER_BLOCK) {
        int packed = 0;
        #pragma unroll
        for (int j = 0; j < LENGTH; ++j) {
            packed |= sbits[t * LENGTH + j] << (LENGTH - 1 - j);
        }
        sidx[t] = ((1 << LENGTH) - 1) ^ packed;
    }
    __syncthreads();

    // Copy: 16 threads per row, one float4 each (256 B/row).
    // Issue all PASSES gathers back-to-back (independent addresses) before
    // any store -> 4 outstanding 16 B loads per thread, ~16 MB in flight
    // across the GPU: latency overlapped.
    const int sub = t >> 4;   // 0..15
    const int pos = t & 15;   // 0..15

    f32x4 v[PASSES];
    #pragma unroll
    for (int p = 0; p < PASSES; ++p) {
        const int r = p * 16 + sub;
        const f32x4* __restrict__ src =
            (const f32x4*)(cats + (size_t)sidx[r] * DIM);
        v[p] = src[pos];   // normal (cached) load: cats reuse is the win
    }

    #pragma unroll
    for (int p = 0; p < PASSES; ++p) {
        const int r = p * 16 + sub;
        f32x4* dst = (f32x4*)(out + (size_t)(row0 + r) * DIM);
        // out is write-once: non-temporal store.
        __builtin_nontemporal_store(v[p], &dst[pos]);
    }
}

extern "C" void kernel_launch(void* const* d_in, const int* in_sizes, int n_in,
                              void* d_out, int out_size, void* d_ws, size_t ws_size,
                              hipStream_t stream) {
    const int* x = (const int*)d_in[0];        // (4096,16,20) int32
    const float* cats = (const float*)d_in[1]; // (2^20, 64) fp32
    float* out = (float*)d_out;                // (4096,16,64) fp32

    dim3 grid(ROWS / ROWS_PER_BLOCK); // 1024 blocks
    dim3 block(THREADS);
    bincat_gather<<<grid, block, 0, stream>>>(x, cats, out);
}